// Round 11
// baseline (106.677 us; speedup 1.0000x reference)
//
#include <hip/hip_runtime.h>
#include <hip/hip_fp16.h>

constexpr int EMB = 256;
constexpr int RELDIMS = 512;
constexpr float FEPS = 1e-6f;
constexpr int RPW = 2;      // rows per wave
constexpr int WPB = 4;      // waves per block

typedef float f4 __attribute__((ext_vector_type(4)));

__device__ __forceinline__ float ftanh(float x) {
    x = fminf(15.f, fmaxf(-15.f, x));
    float t = __expf(2.f * x);
    return (t - 1.f) * __builtin_amdgcn_rcpf(t + 1.f);
}

// ---------- precompute: packed fp16 {ct, wp1} per (rel, dim); word index = h*EMB+d ----------
__global__ __launch_bounds__(256) void boxe_pre(
    const float* __restrict__ rel, int n_rel, unsigned int* __restrict__ pre)
{
    const int r    = (blockIdx.x * blockDim.x + threadIdx.x) >> 6;
    const int lane = threadIdx.x & 63;
    if (r >= n_rel) return;
    const float* __restrict__ rrow = rel + (long)r * (4 * EMB + 2);
    const int d0 = lane * 4;

    float c0[4], c1[4], w0[4], w1[4];
    *(float4*)c0 = *(const float4*)(rrow + d0);
    *(float4*)c1 = *(const float4*)(rrow + EMB + d0);
    *(float4*)w0 = *(const float4*)(rrow + 2 * EMB + d0);
    *(float4*)w1 = *(const float4*)(rrow + 3 * EMB + d0);
    const float bs0 = rrow[4 * EMB + 0];
    const float bs1 = rrow[4 * EMB + 1];

    float wa0[4], wa1[4], ls0 = 0.f, ls1 = 0.f;
#pragma unroll
    for (int j = 0; j < 4; ++j) {
        wa0[j] = fabsf(w0[j]); wa1[j] = fabsf(w1[j]);
        ls0 += __logf(fmaxf(wa0[j], FEPS));
        ls1 += __logf(fmaxf(wa1[j], FEPS));
    }
#pragma unroll
    for (int off = 32; off >= 1; off >>= 1) {
        ls0 += __shfl_xor(ls0, off, 64);
        ls1 += __shfl_xor(ls1, off, 64);
    }
    const float g0 = __expf(ls0 * (1.f / (float)EMB));
    const float g1 = __expf(ls1 * (1.f / (float)EMB));
    const float e0 = (bs0 > 0.f) ? bs0 : (__expf(bs0) - 1.f);
    const float e1 = (bs1 > 0.f) ? bs1 : (__expf(bs1) - 1.f);
    const float s0 = (1.f + e0) / fmaxf(g0, FEPS);
    const float s1 = (1.f + e1) / fmaxf(g1, FEPS);

    unsigned int* __restrict__ prow = pre + (long)r * RELDIMS;
    unsigned int pk[4];
#pragma unroll
    for (int j = 0; j < 4; ++j) {
        __half2 h2 = __floats2half2_rn(ftanh(c0[j]), ftanh(wa0[j] * s0) + 1.f);
        pk[j] = *(unsigned int*)&h2;
    }
    *(uint4*)(prow + d0) = make_uint4(pk[0], pk[1], pk[2], pk[3]);
#pragma unroll
    for (int j = 0; j < 4; ++j) {
        __half2 h2 = __floats2half2_rn(ftanh(c1[j]), ftanh(wa1[j] * s1) + 1.f);
        pk[j] = *(unsigned int*)&h2;
    }
    *(uint4*)(prow + EMB + d0) = make_uint4(pk[0], pk[1], pk[2], pk[3]);
}

// ---------- main: dense per-inst loads (lane owns 4 dims of both heads);
// ---------- 2 rows/wave, all 12 loads issued up front ----------
__global__ __launch_bounds__(256, 6) void boxe_main(
    const float* __restrict__ head, const int* __restrict__ rid,
    const float* __restrict__ tail, const unsigned int* __restrict__ pre,
    float* __restrict__ out)
{
    const int wave = blockIdx.x * WPB + (threadIdx.x >> 6);
    const int lane = threadIdx.x & 63;
    const int b0   = wave * RPW;
    const int d0   = lane * 4;

    const int2 rr = *(const int2*)(rid + b0);

    const float* __restrict__ h0 = head + (size_t)b0 * RELDIMS;
    const float* __restrict__ t0 = tail + (size_t)b0 * RELDIMS;
    const float* __restrict__ h1 = h0 + RELDIMS;
    const float* __restrict__ t1 = t0 + RELDIMS;
    const unsigned int* __restrict__ p0 = pre + (size_t)rr.x * RELDIMS;
    const unsigned int* __restrict__ p1 = pre + (size_t)rr.y * RELDIMS;

    // issue ALL 12 dense 1-KB loads up front (12 KB in flight per wave)
    f4 hp0 = *(const f4*)(h0 + d0);
    f4 hb0 = *(const f4*)(h0 + EMB + d0);
    f4 tp0 = *(const f4*)(t0 + d0);
    f4 tb0 = *(const f4*)(t0 + EMB + d0);
    uint4 pa0 = *(const uint4*)(p0 + d0);
    uint4 pb0 = *(const uint4*)(p0 + EMB + d0);
    f4 hp1 = *(const f4*)(h1 + d0);
    f4 hb1 = *(const f4*)(h1 + EMB + d0);
    f4 tp1 = *(const f4*)(t1 + d0);
    f4 tb1 = *(const f4*)(t1 + EMB + d0);
    uint4 pa1 = *(const uint4*)(p1 + d0);
    uint4 pb1 = *(const uint4*)(p1 + EMB + d0);

    float a00 = 0.f, a01 = 0.f, a10 = 0.f, a11 = 0.f;

    const unsigned int pwa0[4] = {pa0.x, pa0.y, pa0.z, pa0.w};
    const unsigned int pwb0[4] = {pb0.x, pb0.y, pb0.z, pb0.w};
    const unsigned int pwa1[4] = {pa1.x, pa1.y, pa1.z, pa1.w};
    const unsigned int pwb1[4] = {pb1.x, pb1.y, pb1.z, pb1.w};

#pragma unroll
    for (int j = 0; j < 4; ++j) {
        {   // row 0, head 0: bumped = head_pos + tail_bump
            float2 cw = __half22float2(*(const __half2*)&pwa0[j]);
            float ct = cw.x, wp1 = cw.y;
            float bt  = ftanh(hp0[j] + tb0[j]);
            float cd  = fabsf(bt - ct);
            float wv  = wp1 - 1.f;
            float inv = __builtin_amdgcn_rcpf(wp1);
            float kap = 0.5f * wv * (wp1 - inv);
            float d   = (cd <= 0.5f * wv) ? (cd * inv) : fmaf(cd, wp1, -kap);
            a00 = fmaf(d, d, a00);
        }
        {   // row 0, head 1: bumped = tail_pos + head_bump
            float2 cw = __half22float2(*(const __half2*)&pwb0[j]);
            float ct = cw.x, wp1 = cw.y;
            float bt  = ftanh(tp0[j] + hb0[j]);
            float cd  = fabsf(bt - ct);
            float wv  = wp1 - 1.f;
            float inv = __builtin_amdgcn_rcpf(wp1);
            float kap = 0.5f * wv * (wp1 - inv);
            float d   = (cd <= 0.5f * wv) ? (cd * inv) : fmaf(cd, wp1, -kap);
            a01 = fmaf(d, d, a01);
        }
        {   // row 1, head 0
            float2 cw = __half22float2(*(const __half2*)&pwa1[j]);
            float ct = cw.x, wp1 = cw.y;
            float bt  = ftanh(hp1[j] + tb1[j]);
            float cd  = fabsf(bt - ct);
            float wv  = wp1 - 1.f;
            float inv = __builtin_amdgcn_rcpf(wp1);
            float kap = 0.5f * wv * (wp1 - inv);
            float d   = (cd <= 0.5f * wv) ? (cd * inv) : fmaf(cd, wp1, -kap);
            a10 = fmaf(d, d, a10);
        }
        {   // row 1, head 1
            float2 cw = __half22float2(*(const __half2*)&pwb1[j]);
            float ct = cw.x, wp1 = cw.y;
            float bt  = ftanh(tp1[j] + hb1[j]);
            float cd  = fabsf(bt - ct);
            float wv  = wp1 - 1.f;
            float inv = __builtin_amdgcn_rcpf(wp1);
            float kap = 0.5f * wv * (wp1 - inv);
            float d   = (cd <= 0.5f * wv) ? (cd * inv) : fmaf(cd, wp1, -kap);
            a11 = fmaf(d, d, a11);
        }
    }

    // 4 interleaved full-wave butterflies (independent chains -> ILP on DS pipe)
#pragma unroll
    for (int off = 32; off >= 1; off >>= 1) {
        a00 += __shfl_xor(a00, off, 64);
        a01 += __shfl_xor(a01, off, 64);
        a10 += __shfl_xor(a10, off, 64);
        a11 += __shfl_xor(a11, off, 64);
    }
    if (lane == 0) {
        float2 o;
        o.x = -(sqrtf(a00) + sqrtf(a01));
        o.y = -(sqrtf(a10) + sqrtf(a11));
        *(float2*)(out + b0) = o;   // b0 even -> 8B aligned
    }
}

// ---------- fallback: R1 fused kernel ----------
__device__ __forceinline__ float dist2_term(float wabs, float scale, float c, float bm) {
    float w   = ftanh(wabs * scale);
    float ctv = ftanh(c);
    float bt  = ftanh(bm);
    float cd  = fabsf(bt - ctv);
    float wp1 = w + 1.f;
    float inv = __builtin_amdgcn_rcpf(wp1);
    float kappa = 0.5f * w * (wp1 - inv);
    float dist = (cd <= 0.5f * w) ? (cd * inv) : fmaf(cd, wp1, -kappa);
    return dist * dist;
}

__global__ __launch_bounds__(256) void boxe_fused(
    const float* __restrict__ head, const int* __restrict__ rid,
    const float* __restrict__ tail, const float* __restrict__ rel,
    float* __restrict__ out, int batch)
{
    const int b    = (int)(((size_t)blockIdx.x * blockDim.x + threadIdx.x) >> 6);
    const int lane = threadIdx.x & 63;
    if (b >= batch) return;
    const long r = rid[b];
    const float* __restrict__ rrow = rel  + r * (long)(4 * EMB + 2);
    const float* __restrict__ hrow = head + (long)b * RELDIMS;
    const float* __restrict__ trow = tail + (long)b * RELDIMS;
    const int d0 = lane * 4;
    float hp[4], hb[4], tp[4], tb[4], c0[4], c1[4], w0[4], w1[4];
    *(float4*)hp = *(const float4*)(hrow + d0);
    *(float4*)hb = *(const float4*)(hrow + EMB + d0);
    *(float4*)tp = *(const float4*)(trow + d0);
    *(float4*)tb = *(const float4*)(trow + EMB + d0);
    *(float4*)c0 = *(const float4*)(rrow + d0);
    *(float4*)c1 = *(const float4*)(rrow + EMB + d0);
    *(float4*)w0 = *(const float4*)(rrow + 2 * EMB + d0);
    *(float4*)w1 = *(const float4*)(rrow + 3 * EMB + d0);
    const float bs0 = rrow[4 * EMB + 0];
    const float bs1 = rrow[4 * EMB + 1];
    float wa0[4], wa1[4], ls0 = 0.f, ls1 = 0.f;
#pragma unroll
    for (int j = 0; j < 4; ++j) {
        wa0[j] = fabsf(w0[j]); wa1[j] = fabsf(w1[j]);
        ls0 += __logf(fmaxf(wa0[j], FEPS)); ls1 += __logf(fmaxf(wa1[j], FEPS));
    }
#pragma unroll
    for (int off = 32; off >= 1; off >>= 1) {
        ls0 += __shfl_xor(ls0, off, 64); ls1 += __shfl_xor(ls1, off, 64);
    }
    const float g0 = __expf(ls0 * (1.f / 256.f)), g1 = __expf(ls1 * (1.f / 256.f));
    const float e0 = (bs0 > 0.f) ? bs0 : (__expf(bs0) - 1.f);
    const float e1 = (bs1 > 0.f) ? bs1 : (__expf(bs1) - 1.f);
    const float s0 = (1.f + e0) / fmaxf(g0, FEPS);
    const float s1 = (1.f + e1) / fmaxf(g1, FEPS);
    float acc0 = 0.f, acc1 = 0.f;
#pragma unroll
    for (int j = 0; j < 4; ++j) {
        acc0 += dist2_term(wa0[j], s0, c0[j], hp[j] + tb[j]);
        acc1 += dist2_term(wa1[j], s1, c1[j], tp[j] + hb[j]);
    }
#pragma unroll
    for (int off = 32; off >= 1; off >>= 1) {
        acc0 += __shfl_xor(acc0, off, 64); acc1 += __shfl_xor(acc1, off, 64);
    }
    if (lane == 0) out[b] = -(sqrtf(acc0) + sqrtf(acc1));
}

extern "C" void kernel_launch(void* const* d_in, const int* in_sizes, int n_in,
                              void* d_out, int out_size, void* d_ws, size_t ws_size,
                              hipStream_t stream) {
    const float* head = (const float*)d_in[0];
    const int*   rid  = (const int*)d_in[1];
    const float* tail = (const float*)d_in[2];
    const float* rel  = (const float*)d_in[3];
    float* out = (float*)d_out;

    const int batch = out_size;                       // 131072
    const int n_rel = in_sizes[3] / (4 * EMB + 2);    // 1024
    const size_t need = (size_t)n_rel * RELDIMS * sizeof(unsigned int);  // 2 MB

    if (ws_size >= need && batch % (WPB * RPW) == 0) {
        unsigned int* pre = (unsigned int*)d_ws;
        boxe_pre<<<(n_rel + 3) / 4, 256, 0, stream>>>(rel, n_rel, pre);
        const int blocks = batch / (WPB * RPW);       // 16384
        boxe_main<<<blocks, 256, 0, stream>>>(head, rid, tail, pre, out);
    } else {
        const int blocks = (batch + 3) / 4;
        boxe_fused<<<blocks, 256, 0, stream>>>(head, rid, tail, rel, out, batch);
    }
}